// Round 13
// baseline (579.299 us; speedup 1.0000x reference)
//
#include <hip/hip_runtime.h>
#include <hip/hip_bf16.h>

#define NE 64
#define HDIM 1024
#define FDIM 2048
#define TDIM 16384

typedef __attribute__((ext_vector_type(8))) short short8;
typedef __attribute__((ext_vector_type(4))) float f32x4;
typedef unsigned short u16;
typedef unsigned int u32;

__device__ __forceinline__ u16 f2bf(float f) {
  return __bfloat16_as_ushort(__float2bfloat16(f));
}
__device__ __forceinline__ u32 pk2(float a, float b) {
  return (u32)f2bf(a) | ((u32)f2bf(b) << 16);
}

// ---- prep: build M-block map (expert, row0, rowend), BM=128 ----
__global__ void k_prep(const int* __restrict__ tpe, int4* __restrict__ map,
                       int* __restrict__ nblocks) {
  if (threadIdx.x != 0 || blockIdx.x != 0) return;
  int off = 0, nb = 0;
  for (int e = 0; e < NE; ++e) {
    int n = tpe[e];
    for (int r = 0; r < n; r += 128) {
      int re = (r + 128 < n) ? (r + 128) : n;
      map[nb++] = make_int4(e, off + r, off + re, 0);
    }
    off += n;
  }
  *nblocks = nb;
}

// ---- x f32 -> bf16 ----
__global__ void k_conv(const float4* __restrict__ in, uint2* __restrict__ out, int n4) {
  int stride = gridDim.x * blockDim.x;
  for (int i = blockIdx.x * blockDim.x + threadIdx.x; i < n4; i += stride) {
    float4 v = in[i];
    uint2 o;
    o.x = pk2(v.x, v.y);
    o.y = pk2(v.z, v.w);
    out[i] = o;
  }
}

// ---- w2 [e][F][H] f32 -> w2t [e][H][F] bf16 (64x64 tiles, padded LDS) ----
// proven in round 1 (~130us).
__global__ __launch_bounds__(256) void k_transpose(const float* __restrict__ w2,
                                                   u16* __restrict__ w2t) {
  __shared__ float lds[64][65];
  const int bid = blockIdx.x;          // e*512 + ft*16 + ht
  const int e = bid >> 9;
  const int rem = bid & 511;
  const int f0 = (rem >> 4) << 6;
  const int h0 = (rem & 15) << 6;
  const float* src = w2 + (size_t)e * FDIM * HDIM;
  const int tid = threadIdx.x;
#pragma unroll
  for (int i = 0; i < 4; ++i) {
    int slot = i * 256 + tid;
    int r = slot >> 4, c4 = (slot & 15) << 2;
    float4 v = *(const float4*)(src + (size_t)(f0 + r) * HDIM + h0 + c4);
    lds[r][c4 + 0] = v.x; lds[r][c4 + 1] = v.y;
    lds[r][c4 + 2] = v.z; lds[r][c4 + 3] = v.w;
  }
  __syncthreads();
  u16* dst = w2t + (size_t)e * HDIM * FDIM;
#pragma unroll
  for (int i = 0; i < 4; ++i) {
    int slot = i * 256 + tid;
    int rh = slot >> 4, cf4 = (slot & 15) << 2;
    uint2 o;
    o.x = pk2(lds[cf4 + 0][rh], lds[cf4 + 1][rh]);
    o.y = pk2(lds[cf4 + 2][rh], lds[cf4 + 3][rh]);
    *(uint2*)(dst + (size_t)(h0 + rh) * FDIM + f0 + cf4) = o;
  }
}

// ---- grouped GEMM, m97-verbatim skeleton: 128x128 tile, BK=32, 4 waves (2x2),
// single-buffered LDS, 2 plain __syncthreads per K-step, ALL staging via
// global_load_lds, compiler-scheduled waits (NO inline asm, NO launch_bounds,
// NO counted vmcnt, NO sched_barrier). Multi-block TLP (24KB/16KB LDS ->
// 4-6 blocks/CU) hides the barrier drain (m114 mechanism).
// A: bf16 [*][K] rows grouped by expert, linear [128][32] LDS.
// B per expert:
//   BF32=true : B [N][K] f32  -> 4x gload_lds, tile [128][32] f32 (16KB),
//               cvt to bf16 at frag-read time (pk2 x4 per frag).
//   BF32=false: B [N][K] bf16 -> 2x gload_lds, tile [128][32] bf16 (8KB).
template<int K, int N, bool GELU, bool BF32, int NY>
__global__ void k_gemm(
    const u16* __restrict__ A, const void* __restrict__ Bv, void* __restrict__ C,
    const int4* __restrict__ map, const int* __restrict__ nblocks)
{
  const int mblk = (int)blockIdx.x / NY;
  const int nblk = (int)blockIdx.x % NY;
  if (mblk >= *nblocks) return;
  const int4 mi = map[mblk];
  const int e = mi.x, row0 = mi.y, rowend = mi.z;
  const int n0 = nblk << 7;

  __shared__ __align__(16) u16 sa[4096];                    // A [128][32] bf16
  __shared__ __align__(16) u16 sb[BF32 ? 8192 : 4096];      // B [128][32] f32|bf16

  const int tid = threadIdx.x;
  const int wid = tid >> 6, lane = tid & 63;
  const int wr = wid >> 1, wc = wid & 1;
  const int fr = lane & 15, fq = lane >> 4;

  f32x4 acc[4][4];
#pragma unroll
  for (int m = 0; m < 4; ++m)
#pragma unroll
    for (int n = 0; n < 4; ++n) acc[m][n] = (f32x4)0.f;

  const u16*   Bb = (const u16*)Bv + (size_t)e * ((size_t)N * K);
  const float* Bf = (const float*)Bv + (size_t)e * ((size_t)N * K);

  for (int k0 = 0; k0 < K; k0 += 32) {
    // A tile: 128x32 bf16, 2 issues (16B/lane)
#pragma unroll
    for (int i = 0; i < 2; ++i) {
      int slot = i * 256 + tid;                 // row=slot>>2, chunk=slot&3
      int row = row0 + (slot >> 2);
      row = row < TDIM ? row : TDIM - 1;        // tail clamp (rows unused)
      const u16* g = A + (size_t)row * K + k0 + (slot & 3) * 8;
      __builtin_amdgcn_global_load_lds(
          (const __attribute__((address_space(1))) u32*)g,
          (__attribute__((address_space(3))) u32*)(&sa[slot * 8]),
          16, 0, 0);
    }
    if constexpr (BF32) {
      // B tile: 128x32 f32 (16KB), 4 issues; row n = slot>>3, 16B chunk = slot&7
#pragma unroll
      for (int i = 0; i < 4; ++i) {
        int slot = i * 256 + tid;
        const float* g = Bf + (size_t)(n0 + (slot >> 3)) * K + k0 + (slot & 7) * 4;
        __builtin_amdgcn_global_load_lds(
            (const __attribute__((address_space(1))) u32*)g,
            (__attribute__((address_space(3))) u32*)(&sb[slot * 8]),
            16, 0, 0);
      }
    } else {
      // B tile: 128x32 bf16 (8KB), 2 issues
#pragma unroll
      for (int i = 0; i < 2; ++i) {
        int slot = i * 256 + tid;
        const u16* g = Bb + (size_t)(n0 + (slot >> 2)) * K + k0 + (slot & 3) * 8;
        __builtin_amdgcn_global_load_lds(
            (const __attribute__((address_space(1))) u32*)g,
            (__attribute__((address_space(3))) u32*)(&sb[slot * 8]),
            16, 0, 0);
      }
    }
    __syncthreads();   // compiler emits the vmcnt drain

    short8 av[4], bv[4];
#pragma unroll
    for (int m = 0; m < 4; ++m)
      av[m] = *(const short8*)(&sa[(wr * 64 + m * 16 + fr) * 32 + fq * 8]);
#pragma unroll
    for (int n = 0; n < 4; ++n) {
      const int nn = wc * 64 + n * 16 + fr;
      if constexpr (BF32) {
        float4 lo = *(const float4*)(&sb[nn * 64 + fq * 16 + 0]);
        float4 hi = *(const float4*)(&sb[nn * 64 + fq * 16 + 8]);
        union { short8 s; u32 u[4]; } bb;
        bb.u[0] = pk2(lo.x, lo.y); bb.u[1] = pk2(lo.z, lo.w);
        bb.u[2] = pk2(hi.x, hi.y); bb.u[3] = pk2(hi.z, hi.w);
        bv[n] = bb.s;
      } else {
        bv[n] = *(const short8*)(&sb[nn * 32 + fq * 8]);
      }
    }
#pragma unroll
    for (int m = 0; m < 4; ++m)
#pragma unroll
      for (int n = 0; n < 4; ++n)
        acc[m][n] = __builtin_amdgcn_mfma_f32_16x16x32_bf16(av[m], bv[n], acc[m][n], 0, 0, 0);
    __syncthreads();
  }

  // epilogue: C/D layout row=(lane>>4)*4+j, col=lane&15 (m89-verified)
#pragma unroll
  for (int m = 0; m < 4; ++m) {
    const int rb = row0 + wr * 64 + m * 16 + fq * 4;
#pragma unroll
    for (int n = 0; n < 4; ++n) {
      const int col = n0 + wc * 64 + n * 16 + fr;
#pragma unroll
      for (int j = 0; j < 4; ++j) {
        int r = rb + j;
        if (r < rowend) {
          float vv = acc[m][n][j];
          if constexpr (GELU) {
            vv = 0.5f * vv * (1.f + erff(vv * 0.70710678118654752f));
            ((u16*)C)[(size_t)r * N + col] = f2bf(vv);
          } else {
            ((float*)C)[(size_t)r * N + col] = vv;
          }
        }
      }
    }
  }
}

extern "C" void kernel_launch(void* const* d_in, const int* in_sizes, int n_in,
                              void* d_out, int out_size, void* d_ws, size_t ws_size,
                              hipStream_t stream) {
  const float* x  = (const float*)d_in[0];
  const float* w1 = (const float*)d_in[1];
  const float* w2 = (const float*)d_in[2];
  const int*  tpe = (const int*)d_in[3];

  char* ws = (char*)d_ws;
  int4* map     = (int4*)ws;                       // up to 192 entries
  int*  nblocks = (int*)(ws + 4096);
  u16*  xb      = (u16*)(ws + 8192);               // T*H bf16   = 32MB
  u16*  hb      = xb + (size_t)TDIM * HDIM;        // T*F bf16   = 64MB
  u16*  w2t     = hb + (size_t)TDIM * FDIM;        // NE*H*F bf16 = 256MB
  // total ws ~352MB

  k_prep<<<1, 64, 0, stream>>>(tpe, map, nblocks);
  k_conv<<<2048, 256, 0, stream>>>((const float4*)x, (uint2*)xb, (TDIM * HDIM) / 4);
  k_transpose<<<NE * 512, 256, 0, stream>>>(w2, w2t);
  // GEMM1: h = gelu(x @ w1^T)   B=w1 f32 [F][H]=[N][K] k-contig, NY=16
  k_gemm<HDIM, FDIM, true,  true,  16><<<192 * 16, 256, 0, stream>>>(
      xb, (const void*)w1, (void*)hb, map, nblocks);
  // GEMM2: out = h @ w2 = h @ w2t^T   B=w2t bf16 [H][F]=[N][K] k-contig, NY=8
  k_gemm<FDIM, HDIM, false, false, 8><<<192 * 8, 256, 0, stream>>>(
      hb, (const void*)w2t, d_out, map, nblocks);
}

// Round 14
// 489.897 us; speedup vs baseline: 1.1825x; 1.1825x over previous
//
#include <hip/hip_runtime.h>
#include <hip/hip_bf16.h>

#define NE 64
#define HDIM 1024
#define FDIM 2048
#define TDIM 16384

typedef __attribute__((ext_vector_type(8))) short short8;
typedef __attribute__((ext_vector_type(4))) float f32x4;
typedef unsigned short u16;
typedef unsigned int u32;

struct IC0 { static constexpr int v = 0; };
struct IC1 { static constexpr int v = 1; };
template<int W> struct WN { static constexpr int v = W; };

__device__ __forceinline__ u16 f2bf(float f) {
  return __bfloat16_as_ushort(__float2bfloat16(f));
}
__device__ __forceinline__ u32 pk2(float a, float b) {
  return (u32)f2bf(a) | ((u32)f2bf(b) << 16);
}
template<int N> __device__ __forceinline__ void waitv() {
  if constexpr (N == 2)       asm volatile("s_waitcnt vmcnt(2)" ::: "memory");
  else if constexpr (N == 4)  asm volatile("s_waitcnt vmcnt(4)" ::: "memory");
  else if constexpr (N == 8)  asm volatile("s_waitcnt vmcnt(8)" ::: "memory");
  else if constexpr (N == 10) asm volatile("s_waitcnt vmcnt(10)" ::: "memory");
}
__device__ __forceinline__ void waitl() {
  asm volatile("s_waitcnt lgkmcnt(0)" ::: "memory");
}

// ---- prep: build M-block map (expert, row0, rowend), BM=256 ----
__global__ void k_prep(const int* __restrict__ tpe, int4* __restrict__ map,
                       int* __restrict__ nblocks) {
  if (threadIdx.x != 0 || blockIdx.x != 0) return;
  int off = 0, nb = 0;
  for (int e = 0; e < NE; ++e) {
    int n = tpe[e];
    for (int r = 0; r < n; r += 256) {
      int re = (r + 256 < n) ? (r + 256) : n;
      map[nb++] = make_int4(e, off + r, off + re, 0);
    }
    off += n;
  }
  *nblocks = nb;
}

// ---- f32 -> bf16 convert ----
__global__ void k_conv(const float4* __restrict__ in, uint2* __restrict__ out, int n4) {
  int stride = gridDim.x * blockDim.x;
  for (int i = blockIdx.x * blockDim.x + threadIdx.x; i < n4; i += stride) {
    float4 v = in[i];
    uint2 o;
    o.x = pk2(v.x, v.y);
    o.y = pk2(v.z, v.w);
    out[i] = o;
  }
}

// ---- grouped GEMM: 256x128 tile, BK=32, 512 threads (8 waves of 64x64).
// Round-9 proven pipeline (3-rot A gload_lds 2-body flight; B f32 ping-pong
// reg sets 2-body flight; counted vmcnt; unconditional clamped tail issues)
// + THIS ROUND: 2-phase body split with mid s_barrier + s_setprio around each
// 8-MFMA cluster (T5 + phase role-split; scheduling-only, race-free — no LDS
// hazard crosses the mid-barrier; memory-op issue order identical to round 9).
// Steady top-of-body(t) outstanding, age order:
//   A(t)[2], B(t+1)[LB], A(t+1)[2], B(t+2)[LB]
//   -> vmcnt(2+LB) drains exactly A(t)+B(t+1); body(0) peeled: vmcnt(LB).
//   BMODE==1: B [N][K] k-contig  -> 2x float4/thread   (LB=2)
//   BMODE==2: B [K][N] n-contig  -> 8x f32/thread      (LB=8)
template<int K, int N, bool GELU, int BMODE, int NY>
__global__ __launch_bounds__(512) void k_gemm(
    const u16* __restrict__ A, const float* __restrict__ Bf, void* __restrict__ C,
    const int4* __restrict__ map, const int* __restrict__ nblocks)
{
  const int mblk = (int)blockIdx.x / NY;
  const int nblk = (int)blockIdx.x % NY;
  if (mblk >= *nblocks) return;
  const int4 mi = map[mblk];
  const int e = mi.x, row0 = mi.y, rowend = mi.z;
  const int n0 = nblk << 7;
  const int NT = K / 32;                      // 32 or 64, even
  constexpr int LB = (BMODE == 1) ? 2 : 8;    // B vmem ops per body per thread

  __shared__ __align__(16) u16 sa[3][8192];     // A [256][32] bf16 swizzled, 3-rot
  __shared__ __align__(16) u16 sb[2][128 * 40]; // B [128 n][40] bf16, dbuf

  const int tid = threadIdx.x;
  const int wid = tid >> 6, lane = tid & 63;
  const int wr = wid >> 1, wc = wid & 1;      // 4 row-quads x 2 col-halves
  const int fr = lane & 15, fq = lane >> 4;

  f32x4 acc[4][4];
#pragma unroll
  for (int m = 0; m < 4; ++m)
#pragma unroll
    for (int n = 0; n < 4; ++n) acc[m][n] = (f32x4)0.f;

  const float* B = Bf + (size_t)e * ((size_t)N * K);

  float4 rb1[2][2];                 // BMODE1 ping-pong reg sets
  float  rb2[2][8];                 // BMODE2 ping-pong reg sets
  const int bn  = tid & 127;        // BMODE2: owned n-column
  const int oct = tid >> 7;         // BMODE2: k-octet (0..3)

  auto issueA = [&](int t, int buf) {
#pragma unroll
    for (int i = 0; i < 2; ++i) {
      int slot = i * 512 + tid;                 // row=slot>>2, chunk=slot&3
      int r = slot >> 2, c = slot & 3;
      int cs = c ^ ((r >> 1) & 3);              // pre-swizzled source chunk
      int row = row0 + r;
      row = row < TDIM ? row : TDIM - 1;
      const u16* g = A + (size_t)row * K + t * 32 + cs * 8;
      __builtin_amdgcn_global_load_lds(
          (const __attribute__((address_space(1))) u32*)g,
          (__attribute__((address_space(3))) u32*)(&sa[buf][i * 4096 + wid * 512]),
          16, 0, 0);
    }
  };
  auto loadB = [&](int t, auto ic) {
    constexpr int S = decltype(ic)::v;
    if constexpr (BMODE == 1) {
#pragma unroll
      for (int i = 0; i < 2; ++i) {
        int slot = i * 512 + tid;               // n=slot>>3, k16=slot&7
        rb1[S][i] = *(const float4*)(B + (size_t)(n0 + (slot >> 3)) * K + t * 32 + (slot & 7) * 4);
      }
    } else {
      const float* src = B + (size_t)(t * 32 + oct * 8) * N + n0 + bn;
#pragma unroll
      for (int i = 0; i < 8; ++i) rb2[S][i] = src[(size_t)i * N];
    }
  };
  auto writeB = [&](int buf, auto ic) {
    constexpr int S = decltype(ic)::v;
    if constexpr (BMODE == 1) {
#pragma unroll
      for (int i = 0; i < 2; ++i) {
        int slot = i * 512 + tid;
        uint2 o;
        o.x = pk2(rb1[S][i].x, rb1[S][i].y);
        o.y = pk2(rb1[S][i].z, rb1[S][i].w);
        *(uint2*)(&sb[buf][(slot >> 3) * 40 + (slot & 7) * 4]) = o;
      }
    } else {
      uint4 c;
      c.x = pk2(rb2[S][0], rb2[S][1]); c.y = pk2(rb2[S][2], rb2[S][3]);
      c.z = pk2(rb2[S][4], rb2[S][5]); c.w = pk2(rb2[S][6], rb2[S][7]);
      *(uint4*)(&sb[buf][bn * 40 + oct * 8]) = c;   // byte bn*80+oct*16 (80=5x16)
    }
  };

  auto body = [&](int t, auto icCur, auto wn) {
    waitv<decltype(wn)::v>();
    waitl();                        // own ds_writes from prev body drained
    __builtin_amdgcn_s_barrier();
    const int cur3 = t % 3, curb = t & 1, nxtb = curb ^ 1;
    short8 av[4], bv[4];
    // ---- phase 1: A-frags + first B-half, issue A(t+2), MFMA n=0,1 ----
#pragma unroll
    for (int m = 0; m < 4; ++m) {
      const int row = wr * 64 + m * 16 + fr;
      av[m] = *(const short8*)(&sa[cur3][row * 32 + (fq ^ ((row >> 1) & 3)) * 8]);
    }
#pragma unroll
    for (int n = 0; n < 2; ++n)
      bv[n] = *(const short8*)(&sb[curb][(wc * 64 + n * 16 + fr) * 40 + fq * 8]);
    issueA((t + 2 < NT) ? (t + 2) : (NT - 1), (t + 2) % 3);
    __builtin_amdgcn_s_setprio(1);
#pragma unroll
    for (int m = 0; m < 4; ++m)
#pragma unroll
      for (int n = 0; n < 2; ++n)
        acc[m][n] = __builtin_amdgcn_mfma_f32_16x16x32_bf16(av[m], bv[n], acc[m][n], 0, 0, 0);
    __builtin_amdgcn_s_setprio(0);
    __builtin_amdgcn_s_barrier();   // mid-phase barrier (scheduling only)
    // ---- phase 2: second B-half, writeB(t+1), loadB(t+3), MFMA n=2,3 ----
#pragma unroll
    for (int n = 2; n < 4; ++n)
      bv[n] = *(const short8*)(&sb[curb][(wc * 64 + n * 16 + fr) * 40 + fq * 8]);
    writeB(nxtb, icCur);                               // sb[nxt] <- B(t+1)
    loadB((t + 3 < NT) ? (t + 3) : (NT - 1), icCur);   // refill same reg set
    __builtin_amdgcn_s_setprio(1);
#pragma unroll
    for (int m = 0; m < 4; ++m)
#pragma unroll
      for (int n = 2; n < 4; ++n)
        acc[m][n] = __builtin_amdgcn_mfma_f32_16x16x32_bf16(av[m], bv[n], acc[m][n], 0, 0, 0);
    __builtin_amdgcn_s_setprio(0);
  };

  // prologue (order matters for vmcnt age accounting):
  issueA(0, 0);         // A(0) -> sa[0]
  loadB(0, IC0{});      // B(0) -> set0
  issueA(1, 1);         // A(1) -> sa[1]
  loadB(1, IC1{});      // B(1) -> set1
  waitv<2 + LB>();      // drains A(0)+B(0); leaves A(1),B(1)
  writeB(0, IC0{});     // sb[0] <- B(0)
  loadB(2, IC0{});      // B(2) -> set0
  // outstanding: A(1)[2], B(1)[LB], B(2)[LB]

  body(0, IC1{}, WN<LB>{});       // drains A(1)(early)+B(1); leaves B(2)
  body(1, IC0{}, WN<2 + LB>{});   // drains B(2); leaves A(2),B(3)
  for (int t = 2; t < NT; t += 2) {
    body(t,     IC1{}, WN<2 + LB>{});
    body(t + 1, IC0{}, WN<2 + LB>{});
  }

  // epilogue: C/D layout row=(lane>>4)*4+j, col=lane&15
#pragma unroll
  for (int m = 0; m < 4; ++m) {
    const int rb = row0 + wr * 64 + m * 16 + fq * 4;
#pragma unroll
    for (int n = 0; n < 4; ++n) {
      const int col = n0 + wc * 64 + n * 16 + fr;
#pragma unroll
      for (int j = 0; j < 4; ++j) {
        int r = rb + j;
        if (r < rowend) {
          float vv = acc[m][n][j];
          if constexpr (GELU) {
            vv = 0.5f * vv * (1.f + erff(vv * 0.70710678118654752f));
            ((u16*)C)[(size_t)r * N + col] = f2bf(vv);
          } else {
            ((float*)C)[(size_t)r * N + col] = vv;
          }
        }
      }
    }
  }
}

extern "C" void kernel_launch(void* const* d_in, const int* in_sizes, int n_in,
                              void* d_out, int out_size, void* d_ws, size_t ws_size,
                              hipStream_t stream) {
  const float* x  = (const float*)d_in[0];
  const float* w1 = (const float*)d_in[1];
  const float* w2 = (const float*)d_in[2];
  const int*  tpe = (const int*)d_in[3];

  char* ws = (char*)d_ws;
  int4* map     = (int4*)ws;                       // up to 256 entries
  int*  nblocks = (int*)(ws + 4096);
  u16*  xb      = (u16*)(ws + 8192);               // T*H bf16 = 32MB
  u16*  hb      = xb + (size_t)TDIM * HDIM;        // T*F bf16 = 64MB

  k_prep<<<1, 64, 0, stream>>>(tpe, map, nblocks);
  k_conv<<<2048, 256, 0, stream>>>((const float4*)x, (uint2*)xb, (TDIM * HDIM) / 4);
  // GEMM1: h = gelu(x @ w1^T)   B=w1 f32 [F][H] = [N][K], NY=16
  k_gemm<HDIM, FDIM, true,  1, 16><<<128 * 16, 512, 0, stream>>>(
      xb, w1, (void*)hb, map, nblocks);
  // GEMM2: out = h @ w2         B=w2 f32 [F][H] = [K][N], NY=8
  k_gemm<FDIM, HDIM, false, 2, 8><<<128 * 8, 512, 0, stream>>>(
      hb, w2, d_out, map, nblocks);
}

// Round 15
// 471.337 us; speedup vs baseline: 1.2291x; 1.0394x over previous
//
#include <hip/hip_runtime.h>
#include <hip/hip_bf16.h>

#define NE 64
#define HDIM 1024
#define FDIM 2048
#define TDIM 16384

typedef __attribute__((ext_vector_type(8))) short short8;
typedef __attribute__((ext_vector_type(4))) float f32x4;
typedef unsigned short u16;
typedef unsigned int u32;

struct IC0 { static constexpr int v = 0; };
struct IC1 { static constexpr int v = 1; };

__device__ __forceinline__ u16 f2bf(float f) {
  return __bfloat16_as_ushort(__float2bfloat16(f));
}
__device__ __forceinline__ u32 pk2(float a, float b) {
  return (u32)f2bf(a) | ((u32)f2bf(b) << 16);
}
template<int N> __device__ __forceinline__ void waitv() {
  if constexpr (N == 4)       asm volatile("s_waitcnt vmcnt(4)" ::: "memory");
  else if constexpr (N == 16) asm volatile("s_waitcnt vmcnt(16)" ::: "memory");
}
__device__ __forceinline__ void waitl() {
  asm volatile("s_waitcnt lgkmcnt(0)" ::: "memory");
}

// ---- prep: build M-block map (expert, row0, rowend), BM=256 ----
__global__ void k_prep(const int* __restrict__ tpe, int4* __restrict__ map,
                       int* __restrict__ nblocks) {
  if (threadIdx.x != 0 || blockIdx.x != 0) return;
  int off = 0, nb = 0;
  for (int e = 0; e < NE; ++e) {
    int n = tpe[e];
    for (int r = 0; r < n; r += 256) {
      int re = (r + 256 < n) ? (r + 256) : n;
      map[nb++] = make_int4(e, off + r, off + re, 0);
    }
    off += n;
  }
  *nblocks = nb;
}

// ---- f32 -> bf16 convert ----
__global__ void k_conv(const float4* __restrict__ in, uint2* __restrict__ out, int n4) {
  int stride = gridDim.x * blockDim.x;
  for (int i = blockIdx.x * blockDim.x + threadIdx.x; i < n4; i += stride) {
    float4 v = in[i];
    uint2 o;
    o.x = pk2(v.x, v.y);
    o.y = pk2(v.z, v.w);
    out[i] = o;
  }
}

// ---- grouped GEMM: 256x256 tile, BK=32, 512 threads = 8 waves (2 Mx4 N),
// wave tile 128x64 -> 32 MFMA/wave/body (2x the previous density; the one
// axis untouched across rounds 4-14's null scheduling variants).
// Proven round-10 sync skeleton: ONE s_barrier per K-step, counted vmcnt,
// A bf16 gload_lds dbuf (1-body flight, XOR chunk-swizzle both sides),
// B f32 -> ping-pong reg sets (2-body flight) -> pk2 -> ds_write bf16 into
// sb[2] (80B pitch). waitl-before-barrier publishes ds_writes.
// body(t) top age-order: B(t+1)[LB], A(t)[2], B(t+2)[LB]
//   -> vmcnt(LB) drains B(t+1)+A(t), leaves B(t+2). UNIFORM all t incl. 0.
// Tail: unconditional clamped dummy issues (round-7 invariant).
//   BMODE==1: B [N][K] k-contig  -> 4x float4/thread   (LB=4)
//   BMODE==2: B [K][N] n-contig  -> 16x f32/thread     (LB=16)
template<int K, int N, bool GELU, int BMODE, int NY>
__global__ __launch_bounds__(512) void k_gemm(
    const u16* __restrict__ A, const float* __restrict__ Bf, void* __restrict__ C,
    const int4* __restrict__ map, const int* __restrict__ nblocks)
{
  const int mblk = (int)blockIdx.x / NY;
  const int nblk = (int)blockIdx.x % NY;
  if (mblk >= *nblocks) return;
  const int4 mi = map[mblk];
  const int e = mi.x, row0 = mi.y, rowend = mi.z;
  const int n0 = nblk << 8;                   // BN=256
  const int NT = K / 32;                      // 32 or 64, even
  constexpr int LB = (BMODE == 1) ? 4 : 16;   // B vmem ops per body per thread

  __shared__ __align__(16) u16 sa[2][8192];     // A [256][32] bf16 swizzled, dbuf (32KB)
  __shared__ __align__(16) u16 sb[2][256 * 40]; // B [256 n][40] bf16, dbuf (40KB)

  const int tid = threadIdx.x;
  const int wid = tid >> 6, lane = tid & 63;
  const int wr = wid >> 2, wc = wid & 3;      // 2 M-halves x 4 N-quarters
  const int fr = lane & 15, fq = lane >> 4;

  f32x4 acc[8][4];
#pragma unroll
  for (int m = 0; m < 8; ++m)
#pragma unroll
    for (int n = 0; n < 4; ++n) acc[m][n] = (f32x4)0.f;

  const float* B = Bf + (size_t)e * ((size_t)N * K);

  float4 rb1[2][4];                 // BMODE1 ping-pong reg sets
  float  rb2[2][16];                // BMODE2 ping-pong reg sets
  const int bn  = tid & 255;        // BMODE2: owned n-column (0..255)
  const int oct = tid >> 8;         // BMODE2: k-half of 16 (0..1)

  auto issueA = [&](int t, int buf) {
#pragma unroll
    for (int i = 0; i < 2; ++i) {
      int slot = i * 512 + tid;                 // row=slot>>2 (0..255), chunk=slot&3
      int r = slot >> 2, c = slot & 3;
      int cs = c ^ ((r >> 1) & 3);              // pre-swizzled source chunk
      int row = row0 + r;
      row = row < TDIM ? row : TDIM - 1;
      const u16* g = A + (size_t)row * K + t * 32 + cs * 8;
      __builtin_amdgcn_global_load_lds(
          (const __attribute__((address_space(1))) u32*)g,
          (__attribute__((address_space(3))) u32*)(&sa[buf][slot * 8]),
          16, 0, 0);
    }
  };
  auto loadB = [&](int t, auto ic) {
    constexpr int S = decltype(ic)::v;
    if constexpr (BMODE == 1) {
#pragma unroll
      for (int i = 0; i < 4; ++i) {
        int slot = i * 512 + tid;               // n=slot>>3 (0..255), 16B chunk=slot&7
        rb1[S][i] = *(const float4*)(B + (size_t)(n0 + (slot >> 3)) * K + t * 32 + (slot & 7) * 4);
      }
    } else {
      const float* src = B + (size_t)(t * 32 + oct * 16) * N + n0 + bn;
#pragma unroll
      for (int i = 0; i < 16; ++i) rb2[S][i] = src[(size_t)i * N];
    }
  };
  auto writeB = [&](int buf, auto ic) {
    constexpr int S = decltype(ic)::v;
    if constexpr (BMODE == 1) {
#pragma unroll
      for (int i = 0; i < 4; ++i) {
        int slot = i * 512 + tid;
        uint2 o;
        o.x = pk2(rb1[S][i].x, rb1[S][i].y);
        o.y = pk2(rb1[S][i].z, rb1[S][i].w);
        *(uint2*)(&sb[buf][(slot >> 3) * 40 + (slot & 7) * 4]) = o;
      }
    } else {
      uint4 c0, c1;
      c0.x = pk2(rb2[S][0],  rb2[S][1]);  c0.y = pk2(rb2[S][2],  rb2[S][3]);
      c0.z = pk2(rb2[S][4],  rb2[S][5]);  c0.w = pk2(rb2[S][6],  rb2[S][7]);
      c1.x = pk2(rb2[S][8],  rb2[S][9]);  c1.y = pk2(rb2[S][10], rb2[S][11]);
      c1.z = pk2(rb2[S][12], rb2[S][13]); c1.w = pk2(rb2[S][14], rb2[S][15]);
      *(uint4*)(&sb[buf][bn * 40 + oct * 16 + 0]) = c0;   // byte bn*80+oct*32
      *(uint4*)(&sb[buf][bn * 40 + oct * 16 + 8]) = c1;
    }
  };

  auto body = [&](int t, auto icCur) {
    waitv<LB>();         // drains B(t+1)+A(t); leaves B(t+2)
    waitl();             // own ds_writes from prev body drained (publish)
    __builtin_amdgcn_s_barrier();   // ONE barrier per K-step
    const int cur = t & 1, nxt = cur ^ 1;
    short8 av[8], bv[4];
#pragma unroll
    for (int m = 0; m < 8; ++m) {
      const int row = wr * 128 + m * 16 + fr;
      av[m] = *(const short8*)(&sa[cur][row * 32 + (fq ^ ((row >> 1) & 3)) * 8]);
    }
#pragma unroll
    for (int n = 0; n < 4; ++n)
      bv[n] = *(const short8*)(&sb[cur][(wc * 64 + n * 16 + fr) * 40 + fq * 8]);
    // UNCONDITIONAL issues; clamped tile index at tail keeps pattern invariant.
    issueA((t + 1 < NT) ? (t + 1) : (NT - 1), nxt);
    writeB(nxt, icCur);                               // sb[nxt] <- B(t+1) regs
    loadB((t + 3 < NT) ? (t + 3) : (NT - 1), icCur);  // refill same reg set
#pragma unroll
    for (int m = 0; m < 8; ++m)
#pragma unroll
      for (int n = 0; n < 4; ++n)
        acc[m][n] = __builtin_amdgcn_mfma_f32_16x16x32_bf16(av[m], bv[n], acc[m][n], 0, 0, 0);
  };

  // prologue (age order matters):
  issueA(0, 0);         // A(0)[2]
  loadB(0, IC0{});      // B(0)[LB]
  loadB(1, IC1{});      // B(1)[LB]
  waitv<LB>();          // drains A(0)+B(0); leaves B(1)
  writeB(0, IC0{});     // sb[0] <- B(0)
  loadB(2, IC0{});      // B(2)[LB]
  // outstanding: B(1)[LB], B(2)[LB]

  for (int t = 0; t < NT; t += 2) {
    body(t,     IC1{});   // consumes B(t+1) from set1, refills set1 with B(t+3)
    body(t + 1, IC0{});
  }

  // epilogue: C/D layout row=(lane>>4)*4+j, col=lane&15 (m89-verified)
#pragma unroll
  for (int m = 0; m < 8; ++m) {
    const int rb = row0 + wr * 128 + m * 16 + fq * 4;
#pragma unroll
    for (int n = 0; n < 4; ++n) {
      const int col = n0 + wc * 64 + n * 16 + fr;
#pragma unroll
      for (int j = 0; j < 4; ++j) {
        int r = rb + j;
        if (r < rowend) {
          float vv = acc[m][n][j];
          if constexpr (GELU) {
            vv = 0.5f * vv * (1.f + erff(vv * 0.70710678118654752f));
            ((u16*)C)[(size_t)r * N + col] = f2bf(vv);
          } else {
            ((float*)C)[(size_t)r * N + col] = vv;
          }
        }
      }
    }
  }
}

extern "C" void kernel_launch(void* const* d_in, const int* in_sizes, int n_in,
                              void* d_out, int out_size, void* d_ws, size_t ws_size,
                              hipStream_t stream) {
  const float* x  = (const float*)d_in[0];
  const float* w1 = (const float*)d_in[1];
  const float* w2 = (const float*)d_in[2];
  const int*  tpe = (const int*)d_in[3];

  char* ws = (char*)d_ws;
  int4* map     = (int4*)ws;                       // up to 256 entries
  int*  nblocks = (int*)(ws + 4096);
  u16*  xb      = (u16*)(ws + 8192);               // T*H bf16 = 32MB
  u16*  hb      = xb + (size_t)TDIM * HDIM;        // T*F bf16 = 64MB

  k_prep<<<1, 64, 0, stream>>>(tpe, map, nblocks);
  k_conv<<<2048, 256, 0, stream>>>((const float4*)x, (uint2*)xb, (TDIM * HDIM) / 4);
  // max M-blocks at BM=256: sum ceil(n_e/256) <= 128
  // GEMM1: h = gelu(x @ w1^T)   B=w1 f32 [F][H] = [N][K], NY=2048/256=8
  k_gemm<HDIM, FDIM, true,  1, 8><<<128 * 8, 512, 0, stream>>>(
      xb, w1, (void*)hb, map, nblocks);
  // GEMM2: out = h @ w2         B=w2 f32 [F][H] = [K][N], NY=1024/256=4
  k_gemm<FDIM, HDIM, false, 2, 4><<<128 * 4, 512, 0, stream>>>(
      hb, w2, d_out, map, nblocks);
}